// Round 1
// baseline (380.407 us; speedup 1.0000x reference)
//
#include <hip/hip_runtime.h>

#define NB 8
#define NA 32
#define NS 16
#define NT 750
#define NDE 25
#define ND3 58
#define NL 4
#define NDZ 512

// ---------------------------------------------------------------------------
// Kernel 1: pairwise cost[b,s,a] = mean_se/(T*DE) + mean_s1/(T*52) + 10*mean_s2/(T*6)
// one block per (b,s,a) pair; 256 threads grid-stride over the T*D rows.
// ---------------------------------------------------------------------------
__global__ __launch_bounds__(256) void cost_kernel(
    const float* __restrict__ ge, const float* __restrict__ g3,
    const float* __restrict__ pe, const float* __restrict__ p3,
    float* __restrict__ cost)
{
    const int blk = blockIdx.x;          // b*NS*NA + s*NA + a
    const int b   = blk / (NS * NA);
    const int rem = blk % (NS * NA);
    const int s   = rem / NA;
    const int a   = rem % NA;

    const float* pe_p = pe + (size_t)(b * NS + s) * NT * NDE;
    const float* ge_p = ge + (size_t)(b * NA + a) * NT * NDE;
    const float* p3_p = p3 + (size_t)(b * NS + s) * NT * ND3;
    const float* g3_p = g3 + (size_t)(b * NA + a) * NT * ND3;

    float se = 0.f, s1 = 0.f, s2 = 0.f;
    const int tid = threadIdx.x;

    for (int i = tid; i < NT * NDE; i += 256) {
        float d = pe_p[i] - ge_p[i];
        se += d * d;
    }
    for (int i = tid; i < NT * ND3; i += 256) {
        int col = i % ND3;
        float d = p3_p[i] - g3_p[i];
        float dd = d * d;
        if (col < 52) s1 += dd; else s2 += dd;
    }

    // wave(64) reduce then cross-wave via LDS
    #pragma unroll
    for (int o = 32; o > 0; o >>= 1) {
        se += __shfl_down(se, o);
        s1 += __shfl_down(s1, o);
        s2 += __shfl_down(s2, o);
    }
    __shared__ float red[3][4];
    const int lane = tid & 63, wv = tid >> 6;
    if (lane == 0) { red[0][wv] = se; red[1][wv] = s1; red[2][wv] = s2; }
    __syncthreads();
    if (tid == 0) {
        se = red[0][0] + red[0][1] + red[0][2] + red[0][3];
        s1 = red[1][0] + red[1][1] + red[1][2] + red[1][3];
        s2 = red[2][0] + red[2][1] + red[2][2] + red[2][3];
        cost[blk] = se * (1.f / (NT * NDE))
                  + s1 * (1.f / (NT * 52))
                  + s2 * (10.f / (NT * 6));
    }
}

// ---------------------------------------------------------------------------
// Kernel 2: argmin over a for each (b,s)   (first-min tie-break like jnp.argmin)
// ---------------------------------------------------------------------------
__global__ void argmin_kernel(const float* __restrict__ cost, int* __restrict__ idx)
{
    int bs = blockIdx.x * blockDim.x + threadIdx.x;
    if (bs >= NB * NS) return;
    const float* c = cost + bs * NA;
    float best = c[0];
    int bi = 0;
    for (int a = 1; a < NA; ++a) {
        float v = c[a];
        if (v < best) { best = v; bi = a; }
    }
    idx[bs] = bi;
}

// ---------------------------------------------------------------------------
// Kernel 3: reconstruction sums (gathered gt via idx). Block partials -> atomicAdd.
// sums[0]=se, sums[1]=s1, sums[2]=s2
// ---------------------------------------------------------------------------
__global__ __launch_bounds__(256) void rec_kernel(
    const float* __restrict__ ge, const float* __restrict__ g3,
    const float* __restrict__ pe, const float* __restrict__ p3,
    const int* __restrict__ idx, float* __restrict__ sums)
{
    float se = 0.f, s1 = 0.f, s2 = 0.f;
    const int NE = NB * NS * NT * NDE;
    const int N3 = NB * NS * NT * ND3;
    const int stride = gridDim.x * blockDim.x;
    const int start = blockIdx.x * blockDim.x + threadIdx.x;

    for (int i = start; i < NE; i += stride) {
        int bs = i / (NT * NDE);
        int te = i - bs * (NT * NDE);
        int b  = bs / NS;
        int j  = (b * NA + idx[bs]) * (NT * NDE) + te;
        float d = pe[i] - ge[j];
        se += d * d;
    }
    for (int i = start; i < N3; i += stride) {
        int bs = i / (NT * ND3);
        int td = i - bs * (NT * ND3);
        int col = td % ND3;
        int b  = bs / NS;
        int j  = (b * NA + idx[bs]) * (NT * ND3) + td;
        float d = p3[i] - g3[j];
        float dd = d * d;
        if (col < 52) s1 += dd; else s2 += dd;
    }

    #pragma unroll
    for (int o = 32; o > 0; o >>= 1) {
        se += __shfl_down(se, o);
        s1 += __shfl_down(s1, o);
        s2 += __shfl_down(s2, o);
    }
    __shared__ float red[3][4];
    const int lane = threadIdx.x & 63, wv = threadIdx.x >> 6;
    if (lane == 0) { red[0][wv] = se; red[1][wv] = s1; red[2][wv] = s2; }
    __syncthreads();
    if (threadIdx.x == 0) {
        se = red[0][0] + red[0][1] + red[0][2] + red[0][3];
        s1 = red[1][0] + red[1][1] + red[1][2] + red[1][3];
        s2 = red[2][0] + red[2][1] + red[2][2] + red[2][3];
        atomicAdd(&sums[0], se);
        atomicAdd(&sums[1], s1);
        atomicAdd(&sums[2], s2);
    }
}

// ---------------------------------------------------------------------------
// Kernel 4: KL sum -> sums[3]
// ---------------------------------------------------------------------------
__global__ __launch_bounds__(256) void kl_kernel(
    const float* __restrict__ mu, const float* __restrict__ sc,
    float* __restrict__ sums)
{
    float k = 0.f;
    const int N = NL * NB * NS * NDZ;
    const int stride = gridDim.x * blockDim.x;
    for (int i = blockIdx.x * blockDim.x + threadIdx.x; i < N; i += stride) {
        float m = mu[i], sg = sc[i];
        k += -logf(sg) + 0.5f * (sg * sg + m * m - 1.0f);
    }
    #pragma unroll
    for (int o = 32; o > 0; o >>= 1) k += __shfl_down(k, o);
    __shared__ float red[4];
    const int lane = threadIdx.x & 63, wv = threadIdx.x >> 6;
    if (lane == 0) red[wv] = k;
    __syncthreads();
    if (threadIdx.x == 0) {
        atomicAdd(&sums[3], red[0] + red[1] + red[2] + red[3]);
    }
}

// ---------------------------------------------------------------------------
// Kernel 5: finalize -> d_out[0..2] = loss, rec_loss, kld_loss
// ---------------------------------------------------------------------------
__global__ void finalize_kernel(const float* __restrict__ sums, float* __restrict__ out)
{
    float rec = sums[0] * (1.f / ((float)NB * NS * NT * NDE))
              + sums[1] * (1.f / ((float)NB * NS * NT * 52))
              + sums[2] * (10.f / ((float)NB * NS * NT * 6));
    float kld = sums[3] * (1.f / ((float)NL * NB * NS * NDZ));
    out[0] = rec + 0.0002f * kld;
    out[1] = rec;
    out[2] = kld;
}

extern "C" void kernel_launch(void* const* d_in, const int* in_sizes, int n_in,
                              void* d_out, int out_size, void* d_ws, size_t ws_size,
                              hipStream_t stream)
{
    const float* ge = (const float*)d_in[0];   // gt_emotion   [NB*NA, NT, NDE]
    const float* g3 = (const float*)d_in[1];   // gt_3dmm      [NB*NA, NT, ND3]
    const float* pe = (const float*)d_in[2];   // pred_emotion [NB*NS, NT, NDE]
    const float* p3 = (const float*)d_in[3];   // pred_3dmm    [NB*NS, NT, ND3]
    const float* mu = (const float*)d_in[4];   // dist_mu      [NL, NB*NS, NDZ]
    const float* sc = (const float*)d_in[5];   // dist_scale   [NL, NB*NS, NDZ]

    float* cost = (float*)d_ws;                               // 4096 floats
    int*   idx  = (int*)((char*)d_ws + NB * NS * NA * 4);     // 128 ints
    float* sums = (float*)((char*)d_ws + NB * NS * NA * 4 + NB * NS * 4); // 4 floats

    hipMemsetAsync(sums, 0, 4 * sizeof(float), stream);

    cost_kernel<<<NB * NS * NA, 256, 0, stream>>>(ge, g3, pe, p3, cost);
    argmin_kernel<<<1, 128, 0, stream>>>(cost, idx);
    rec_kernel<<<1024, 256, 0, stream>>>(ge, g3, pe, p3, idx, sums);
    kl_kernel<<<256, 256, 0, stream>>>(mu, sc, sums);
    finalize_kernel<<<1, 1, 0, stream>>>(sums, (float*)d_out);
}

// Round 2
// 211.033 us; speedup vs baseline: 1.8026x; 1.8026x over previous
//
#include <hip/hip_runtime.h>

#define NB 8
#define NA 32
#define NS 16
#define NT 750
#define NDE 25
#define ND3 58
#define KE (NT * NDE)   // 18750  flattened emotion K per row
#define K3 (NT * ND3)   // 43500  flattened 3dmm K per row
#define NL 4
#define NDZ 512

#define KC 256          // LDS chunk (floats per row)
#define SLAB 1024       // K covered per block (4 chunks)
#define SE_SLABS 19     // ceil(18750/1024)
#define S3_SLABS 43     // ceil(43500/1024)
#define SLABS_PER_B (SE_SLABS + S3_SLABS)   // 62

// ---------------------------------------------------------------------------
// cost[b,s,a] = se/(T*DE) + s1/(T*52) + 10*s2/(T*6), computed as a single
// weighted SSD by scaling staged values with sqrt(weight).
// Grid: NB * 62 blocks. Block: 256 thr = 8 ksub-groups x 32 tile-positions;
// each position owns a 4s x 4a register tile (16 accumulators).
// ---------------------------------------------------------------------------
__global__ __launch_bounds__(256) void cost_kernel(
    const float* __restrict__ ge, const float* __restrict__ g3,
    const float* __restrict__ pe, const float* __restrict__ p3,
    float* __restrict__ cost)
{
    __shared__ float lds[48][KC + 1];   // rows 0..15 = pred, 16..47 = gt; +1 pad

    const int blk  = blockIdx.x;
    const int b    = blk / SLABS_PER_B;
    const int slab = blk % SLABS_PER_B;
    const bool isE = slab < SE_SLABS;
    const int k0   = (isE ? slab : (slab - SE_SLABS)) * SLAB;
    const int K    = isE ? KE : K3;

    const float* __restrict__ srcP = isE ? pe + (size_t)b * NS * KE
                                         : p3 + (size_t)b * NS * K3;
    const float* __restrict__ srcG = isE ? ge + (size_t)b * NA * KE
                                         : g3 + (size_t)b * NA * K3;

    const float swE = sqrtf(1.0f / (float)KE);
    const float sw1 = sqrtf(1.0f / (float)(NT * 52));
    const float sw2 = sqrtf(10.0f / (float)(NT * 6));

    const int tid   = threadIdx.x;
    const int pos   = tid & 31;          // tile position
    const int ksub  = tid >> 5;          // 0..7, each handles 32 k of the chunk
    const int sbase = (pos >> 3) * 4;        // pred row base in lds
    const int abase = (pos & 7) * 4 + 16;    // gt   row base in lds

    float acc[4][4];
    #pragma unroll
    for (int i = 0; i < 4; ++i)
        #pragma unroll
        for (int j = 0; j < 4; ++j) acc[i][j] = 0.f;

    for (int c = 0; c < SLAB / KC; ++c) {
        const int kbase = k0 + c * KC;

        // ---- stage: thread `tid` loads column k = kbase+tid of every row ----
        {
            const int k = kbase + tid;
            const bool inb = (k < K);
            float sw = swE;
            if (!isE) { const int col = k % ND3; sw = (col < 52) ? sw1 : sw2; }
            #pragma unroll 4
            for (int r = 0; r < 48; ++r) {
                float raw = 0.f;
                if (inb) raw = (r < 16) ? srcP[(size_t)r * K + k]
                                        : srcG[(size_t)(r - 16) * K + k];
                lds[r][tid] = raw * sw;
            }
        }
        __syncthreads();

        // ---- compute: 32 k-values for this ksub, 4x4 register tile ----
        #pragma unroll 4
        for (int q = 0; q < 32; ++q) {
            const int kk = ksub * 32 + q;
            float p[4], g[4];
            #pragma unroll
            for (int i = 0; i < 4; ++i) p[i] = lds[sbase + i][kk];
            #pragma unroll
            for (int j = 0; j < 4; ++j) g[j] = lds[abase + j][kk];
            #pragma unroll
            for (int i = 0; i < 4; ++i)
                #pragma unroll
                for (int j = 0; j < 4; ++j) {
                    const float d = p[i] - g[j];
                    acc[i][j] += d * d;
                }
        }
        __syncthreads();
    }

    // ---- reduce across the 8 ksub replicas ----
    float accf[16];
    #pragma unroll
    for (int i = 0; i < 4; ++i)
        #pragma unroll
        for (int j = 0; j < 4; ++j) accf[i * 4 + j] = acc[i][j];

    #pragma unroll
    for (int i = 0; i < 16; ++i) accf[i] += __shfl_xor(accf[i], 32);

    float* red = (float*)lds;            // [4 waves][32 pos][16] = 2048 floats
    const int wv = tid >> 6, lane = tid & 63;
    if (lane < 32) {
        #pragma unroll
        for (int i = 0; i < 16; ++i) red[(wv * 32 + pos) * 16 + i] = accf[i];
    }
    __syncthreads();

    for (int o = tid; o < 512; o += 256) {
        const int p_ = o >> 4, ij = o & 15;
        const float v = red[(0 * 32 + p_) * 16 + ij] + red[(1 * 32 + p_) * 16 + ij]
                      + red[(2 * 32 + p_) * 16 + ij] + red[(3 * 32 + p_) * 16 + ij];
        const int i = ij >> 2, j = ij & 3;
        const int s = ((p_ >> 3) << 2) + i;
        const int a = ((p_ & 7) << 2) + j;
        atomicAdd(&cost[b * (NS * NA) + s * NA + a], v);
    }
}

// ---------------------------------------------------------------------------
// KL sum -> sums[3]
// ---------------------------------------------------------------------------
__global__ __launch_bounds__(256) void kl_kernel(
    const float* __restrict__ mu, const float* __restrict__ sc,
    float* __restrict__ sums)
{
    float k = 0.f;
    const int N = NL * NB * NS * NDZ;
    const int stride = gridDim.x * blockDim.x;
    for (int i = blockIdx.x * blockDim.x + threadIdx.x; i < N; i += stride) {
        const float m = mu[i], sg = sc[i];
        k += -logf(sg) + 0.5f * (sg * sg + m * m - 1.0f);
    }
    #pragma unroll
    for (int o = 32; o > 0; o >>= 1) k += __shfl_down(k, o);
    __shared__ float red[4];
    const int lane = threadIdx.x & 63, wv = threadIdx.x >> 6;
    if (lane == 0) red[wv] = k;
    __syncthreads();
    if (threadIdx.x == 0)
        atomicAdd(&sums[3], red[0] + red[1] + red[2] + red[3]);
}

// ---------------------------------------------------------------------------
// finalize: rec_loss = mean_{b,s} min_a cost[b,s,a]  (argmin+gather folded in)
// ---------------------------------------------------------------------------
__global__ __launch_bounds__(128) void finalize_kernel(
    const float* __restrict__ cost, const float* __restrict__ sums,
    float* __restrict__ out)
{
    const int t = threadIdx.x;           // 128 = NB*NS
    const float* c = cost + t * NA;
    float m = c[0];
    #pragma unroll
    for (int a = 1; a < NA; ++a) m = fminf(m, c[a]);

    #pragma unroll
    for (int o = 32; o > 0; o >>= 1) m += __shfl_down(m, o);
    __shared__ float r2[2];
    if ((t & 63) == 0) r2[t >> 6] = m;
    __syncthreads();
    if (t == 0) {
        const float rec = (r2[0] + r2[1]) * (1.0f / (NB * NS));
        const float kld = sums[3] * (1.0f / ((float)NL * NB * NS * NDZ));
        out[0] = rec + 0.0002f * kld;
        out[1] = rec;
        out[2] = kld;
    }
}

extern "C" void kernel_launch(void* const* d_in, const int* in_sizes, int n_in,
                              void* d_out, int out_size, void* d_ws, size_t ws_size,
                              hipStream_t stream)
{
    const float* ge = (const float*)d_in[0];
    const float* g3 = (const float*)d_in[1];
    const float* pe = (const float*)d_in[2];
    const float* p3 = (const float*)d_in[3];
    const float* mu = (const float*)d_in[4];
    const float* sc = (const float*)d_in[5];

    float* cost = (float*)d_ws;                       // 4096 floats
    float* sums = cost + NB * NS * NA;                // 4 floats

    hipMemsetAsync(d_ws, 0, (NB * NS * NA + 4) * sizeof(float), stream);

    cost_kernel<<<NB * SLABS_PER_B, 256, 0, stream>>>(ge, g3, pe, p3, cost);
    kl_kernel<<<128, 256, 0, stream>>>(mu, sc, sums);
    finalize_kernel<<<1, 128, 0, stream>>>(cost, sums, (float*)d_out);
}

// Round 3
// 178.747 us; speedup vs baseline: 2.1282x; 1.1806x over previous
//
#include <hip/hip_runtime.h>

#define NB 8
#define NA 32
#define NS 16
#define NT 750
#define NDE 25
#define ND3 58
#define KE (NT * NDE)   // 18750
#define K3 (NT * ND3)   // 43500
#define NL 4
#define NDZ 512
#define NKL (NL * NB * NS * NDZ)   // 262144

#define POS_PER_B 8     // 2 s-tiles x 4 a-tiles, 8x8 elems per thread
#define SLABS 16        // 5 emotion + 11 3dmm k-slabs per (b,pos)
#define SE_SLABS 5
#define SE_CHUNK 3750   // KE / 5 exactly
#define S3_CHUNK 3955   // ceil(K3 / 11)
#define COST_BLOCKS (NB * POS_PER_B * SLABS)   // 1024
#define KL_BLOCKS 64
#define KL_PER_THR (NKL / (KL_BLOCKS * 256))   // 16

// sqrt of the per-term weights (folded into both operands at load)
#define SW_E  0.0073029674f   // sqrt(1/18750)
#define SW_1  0.0050637127f   // sqrt(1/39000)
#define SW_2  0.0471404521f   // sqrt(10/4500)

__device__ __forceinline__ void tile_step(
    const float* __restrict__ srcP, const float* __restrict__ srcG,
    int K, int k, float sw, float acc[64])
{
    float p[8], g[8];
    #pragma unroll
    for (int i = 0; i < 8; ++i) p[i] = srcP[i * K + k] * sw;
    #pragma unroll
    for (int j = 0; j < 8; ++j) g[j] = srcG[j * K + k] * sw;
    #pragma unroll
    for (int i = 0; i < 8; ++i)
        #pragma unroll
        for (int j = 0; j < 8; ++j) {
            const float d = p[i] - g[j];
            acc[i * 8 + j] = fmaf(d, d, acc[i * 8 + j]);
        }
}

// blocks [0, COST_BLOCKS): pairwise weighted-SSD partials -> wsCost
// blocks [COST_BLOCKS, COST_BLOCKS+KL_BLOCKS): KL partial sums -> wsKL
__global__ __launch_bounds__(256) void fused_kernel(
    const float* __restrict__ ge, const float* __restrict__ g3,
    const float* __restrict__ pe, const float* __restrict__ p3,
    const float* __restrict__ mu, const float* __restrict__ sc,
    float* __restrict__ wsCost, float* __restrict__ wsKL)
{
    const int blk = blockIdx.x;
    const int tid = threadIdx.x;
    __shared__ float red[4][64];

    if (blk >= COST_BLOCKS) {
        // ---------------- KL part ----------------
        const int kb = blk - COST_BLOCKS;
        float ks = 0.f;
        #pragma unroll
        for (int it = 0; it < KL_PER_THR; ++it) {
            const int i = kb * (256 * KL_PER_THR) + it * 256 + tid;
            const float m = mu[i], sg = sc[i];
            ks += 0.5f * (sg * sg + m * m - 1.0f) - logf(sg);
        }
        #pragma unroll
        for (int o = 32; o > 0; o >>= 1) ks += __shfl_xor(ks, o);
        const int lane = tid & 63, w = tid >> 6;
        if (lane == 0) red[0][w] = ks;
        __syncthreads();
        if (tid == 0) wsKL[kb] = red[0][0] + red[0][1] + red[0][2] + red[0][3];
        return;
    }

    // ---------------- pairwise cost part ----------------
    const int b    = blk / (POS_PER_B * SLABS);
    const int rem  = blk % (POS_PER_B * SLABS);
    const int pos  = rem / SLABS;
    const int slab = rem % SLABS;
    const int s0   = (pos >> 2) * 8;
    const int a0   = (pos & 3) * 8;

    const bool isE = slab < SE_SLABS;
    const int  K   = isE ? KE : K3;
    const int  k0  = isE ? slab * SE_CHUNK : (slab - SE_SLABS) * S3_CHUNK;
    const int  kend = isE ? k0 + SE_CHUNK : min(k0 + S3_CHUNK, K3);

    const float* __restrict__ srcP = isE ? pe + (size_t)(b * NS + s0) * KE
                                         : p3 + (size_t)(b * NS + s0) * K3;
    const float* __restrict__ srcG = isE ? ge + (size_t)(b * NA + a0) * KE
                                         : g3 + (size_t)(b * NA + a0) * K3;

    float acc[64];
    #pragma unroll
    for (int i = 0; i < 64; ++i) acc[i] = 0.f;

    if (isE) {
        for (int k = k0 + tid; k < kend; k += 256)
            tile_step(srcP, srcG, K, k, SW_E, acc);
    } else {
        int col = (k0 + tid) % ND3;
        for (int k = k0 + tid; k < kend; k += 256) {
            const float sw = (col < 52) ? SW_1 : SW_2;
            tile_step(srcP, srcG, K, k, sw, acc);
            col += 256 % ND3;                 // 24
            if (col >= ND3) col -= ND3;
        }
    }

    // value-splitting butterfly: 63 shfl+add; lane L ends with total for
    // acc index bitrev6(L) in acc[0].
    const int lane = tid & 63;
    int n = 64;
    #pragma unroll
    for (int step = 0; step < 6; ++step) {
        const int o = 1 << step;
        const bool hi = (lane & o) != 0;
        const int h = n >> 1;
        #pragma unroll
        for (int m = 0; m < h; ++m) {
            const float send = hi ? acc[m] : acc[m + h];
            const float recv = __shfl_xor(send, o);
            acc[m] = (hi ? acc[m + h] : acc[m]) + recv;
        }
        n = h;
    }

    const int w = tid >> 6;
    red[w][__brev((unsigned)lane) >> 26] = acc[0];
    __syncthreads();
    if (tid < 64)
        wsCost[blk * 64 + tid] = red[0][tid] + red[1][tid] + red[2][tid] + red[3][tid];
}

// 1 block x 1024 threads: sum slab partials, min over a, mean, add KL.
__global__ __launch_bounds__(1024) void finalize_kernel(
    const float* __restrict__ wsCost, const float* __restrict__ wsKL,
    float* __restrict__ out)
{
    const int t = threadIdx.x;
    const int b  = t >> 7;
    const int s  = (t >> 3) & 15;
    const int a4 = t & 7;                 // owns a = a4*4 .. a4*4+3
    const int ptile = s >> 3, irow = s & 7;

    float mn = 1e30f;
    #pragma unroll
    for (int q = 0; q < 4; ++q) {
        const int a   = a4 * 4 + q;
        const int pos = ptile * 4 + (a >> 3);
        const int j   = a & 7;
        const float* src = wsCost + ((b * POS_PER_B + pos) * SLABS) * 64 + irow * 8 + j;
        float sum = 0.f;
        #pragma unroll
        for (int slab = 0; slab < SLABS; ++slab) sum += src[slab * 64];
        mn = fminf(mn, sum);
    }
    // min across the 8 threads sharing (b,s)
    mn = fminf(mn, __shfl_xor(mn, 1));
    mn = fminf(mn, __shfl_xor(mn, 2));
    mn = fminf(mn, __shfl_xor(mn, 4));

    float contrib = ((t & 7) == 0) ? mn : 0.f;
    #pragma unroll
    for (int o = 32; o > 0; o >>= 1) contrib += __shfl_xor(contrib, o);

    __shared__ float r2[16];
    if ((t & 63) == 0) r2[t >> 6] = contrib;

    float kl = (t < 64) ? wsKL[t] : 0.f;
    #pragma unroll
    for (int o = 32; o > 0; o >>= 1) kl += __shfl_xor(kl, o);

    __syncthreads();
    if (t == 0) {
        float rec = 0.f;
        #pragma unroll
        for (int w = 0; w < 16; ++w) rec += r2[w];
        rec *= (1.0f / (NB * NS));
        const float kld = kl * (1.0f / (float)NKL);
        out[0] = fmaf(0.0002f, kld, rec);
        out[1] = rec;
        out[2] = kld;
    }
}

extern "C" void kernel_launch(void* const* d_in, const int* in_sizes, int n_in,
                              void* d_out, int out_size, void* d_ws, size_t ws_size,
                              hipStream_t stream)
{
    const float* ge = (const float*)d_in[0];
    const float* g3 = (const float*)d_in[1];
    const float* pe = (const float*)d_in[2];
    const float* p3 = (const float*)d_in[3];
    const float* mu = (const float*)d_in[4];
    const float* sc = (const float*)d_in[5];

    float* wsCost = (float*)d_ws;                      // 65536 floats
    float* wsKL   = wsCost + COST_BLOCKS * 64;         // 64 floats

    fused_kernel<<<COST_BLOCKS + KL_BLOCKS, 256, 0, stream>>>(
        ge, g3, pe, p3, mu, sc, wsCost, wsKL);
    finalize_kernel<<<1, 1024, 0, stream>>>(wsCost, wsKL, (float*)d_out);
}

// Round 4
// 156.441 us; speedup vs baseline: 2.4316x; 1.1426x over previous
//
#include <hip/hip_runtime.h>

#define NB 8
#define NA 32
#define NS 16
#define KE 18750        // 750*25 emotion K per row
#define K3 43500        // 750*58 3dmm K per row
#define ND3 58
#define NKL 262144      // 4*8*16*512

#define POS_PER_B 8     // 2 s-tiles x 4 a-tiles (8x8 per thread)
#define SE_SLABS 10
#define S3_SLABS 22
#define SLABS 32
#define CH_E 1876       // even; 10*1876 = 18760 >= 18750
#define CH_3 1978       // even; 22*1978 = 43516 >= 43500
#define COST_BLOCKS (NB * POS_PER_B * SLABS)   // 2048
#define KL_BLOCKS 64
#define KL_PER_THR (NKL / (KL_BLOCKS * 256))   // 16

// sqrt of per-term weights, folded into both operands at load
#define SW_E  0.0073029674f   // sqrt(1/18750)
#define SW_1  0.0050637127f   // sqrt(1/39000)
#define SW_2  0.0471404521f   // sqrt(10/4500)

// blocks [0, COST_BLOCKS): pairwise weighted-SSD slab partials -> atomic cost[4096]
// blocks [COST_BLOCKS, +KL_BLOCKS): KL partial sums -> atomic klsum
__global__ __launch_bounds__(256, 4) void fused_kernel(
    const float* __restrict__ ge, const float* __restrict__ g3,
    const float* __restrict__ pe, const float* __restrict__ p3,
    const float* __restrict__ mu, const float* __restrict__ sc,
    float* __restrict__ cost, float* __restrict__ klsum)
{
    const int blk = blockIdx.x;
    const int tid = threadIdx.x;
    __shared__ float red[4][64];

    if (blk >= COST_BLOCKS) {
        // ---------------- KL part ----------------
        const int kb = blk - COST_BLOCKS;
        float ks = 0.f;
        #pragma unroll
        for (int it = 0; it < KL_PER_THR; ++it) {
            const int i = kb * (256 * KL_PER_THR) + it * 256 + tid;
            const float m = mu[i], sg = sc[i];
            ks += 0.5f * (sg * sg + m * m - 1.0f) - logf(sg);
        }
        #pragma unroll
        for (int o = 32; o > 0; o >>= 1) ks += __shfl_xor(ks, o);
        const int lane = tid & 63, w = tid >> 6;
        if (lane == 0) red[0][w] = ks;
        __syncthreads();
        if (tid == 0)
            atomicAdd(klsum, red[0][0] + red[0][1] + red[0][2] + red[0][3]);
        return;
    }

    // ---------------- pairwise cost part ----------------
    const int b    = blk >> 8;           // / (POS_PER_B*SLABS)
    const int rem  = blk & 255;
    const int pos  = rem >> 5;
    const int slab = rem & 31;
    const int s0   = (pos >> 2) * 8;
    const int a0   = (pos & 3) * 8;

    const bool isE = slab < SE_SLABS;
    const int  KH  = (isE ? KE : K3) >> 1;                  // row stride in float2
    const int  c0  = isE ? slab * CH_E : (slab - SE_SLABS) * CH_3;  // float offset, even
    const int  kk0 = (c0 >> 1) + tid;                       // float2 index start
    const int  kkend = min((c0 + (isE ? CH_E : CH_3)) >> 1, KH);

    const float2* __restrict__ P = (const float2*)(isE ? pe + (size_t)(b * NS + s0) * KE
                                                       : p3 + (size_t)(b * NS + s0) * K3);
    const float2* __restrict__ G = (const float2*)(isE ? ge + (size_t)(b * NA + a0) * KE
                                                       : g3 + (size_t)(b * NA + a0) * K3);

    float acc[64];
    #pragma unroll
    for (int i = 0; i < 64; ++i) acc[i] = 0.f;

    if (isE) {
        for (int kk = kk0; kk < kkend; kk += 256) {
            float2 p[8], g[8];
            #pragma unroll
            for (int i = 0; i < 8; ++i) { p[i] = P[i * KH + kk]; }
            #pragma unroll
            for (int j = 0; j < 8; ++j) { g[j] = G[j * KH + kk]; }
            #pragma unroll
            for (int i = 0; i < 8; ++i) { p[i].x *= SW_E; p[i].y *= SW_E; }
            #pragma unroll
            for (int j = 0; j < 8; ++j) { g[j].x *= SW_E; g[j].y *= SW_E; }
            #pragma unroll
            for (int i = 0; i < 8; ++i)
                #pragma unroll
                for (int j = 0; j < 8; ++j) {
                    const float d0 = p[i].x - g[j].x;
                    const float d1 = p[i].y - g[j].y;
                    float t = fmaf(d0, d0, acc[i * 8 + j]);
                    acc[i * 8 + j] = fmaf(d1, d1, t);
                }
        }
    } else {
        // col = (2*kk) % 58; both comps of a float2 share the same weight side
        // (52 is even), so one select per iteration.
        int col = (2 * kk0) % ND3;
        for (int kk = kk0; kk < kkend; kk += 256) {
            const float sw = (col < 52) ? SW_1 : SW_2;
            col += 48; if (col >= ND3) col -= ND3;   // advance (512 % 58)
            float2 p[8], g[8];
            #pragma unroll
            for (int i = 0; i < 8; ++i) { p[i] = P[i * KH + kk]; }
            #pragma unroll
            for (int j = 0; j < 8; ++j) { g[j] = G[j * KH + kk]; }
            #pragma unroll
            for (int i = 0; i < 8; ++i) { p[i].x *= sw; p[i].y *= sw; }
            #pragma unroll
            for (int j = 0; j < 8; ++j) { g[j].x *= sw; g[j].y *= sw; }
            #pragma unroll
            for (int i = 0; i < 8; ++i)
                #pragma unroll
                for (int j = 0; j < 8; ++j) {
                    const float d0 = p[i].x - g[j].x;
                    const float d1 = p[i].y - g[j].y;
                    float t = fmaf(d0, d0, acc[i * 8 + j]);
                    acc[i * 8 + j] = fmaf(d1, d1, t);
                }
        }
    }

    // value-splitting butterfly: 63 shfl+add; lane L ends with the total for
    // acc flat-index bitrev6(L) in acc[0].
    const int lane = tid & 63;
    int n = 64;
    #pragma unroll
    for (int step = 0; step < 6; ++step) {
        const int o = 1 << step;
        const bool hi = (lane & o) != 0;
        const int h = n >> 1;
        #pragma unroll
        for (int m = 0; m < h; ++m) {
            const float send = hi ? acc[m] : acc[m + h];
            const float recv = __shfl_xor(send, o);
            acc[m] = (hi ? acc[m + h] : acc[m]) + recv;
        }
        n = h;
    }

    const int w = tid >> 6;
    red[w][__brev((unsigned)lane) >> 26] = acc[0];
    __syncthreads();
    if (tid < 64) {
        const float v = red[0][tid] + red[1][tid] + red[2][tid] + red[3][tid];
        const int i = tid >> 3, j = tid & 7;
        atomicAdd(&cost[b * (NS * NA) + (s0 + i) * NA + (a0 + j)], v);
    }
}

// 1 block x 128 threads: thread t = (b,s); min over a, mean, add KL.
__global__ __launch_bounds__(128) void finalize_kernel(
    const float* __restrict__ cost, const float* __restrict__ klsum,
    float* __restrict__ out)
{
    const int t = threadIdx.x;
    const float4* row = (const float4*)(cost + t * NA);
    float mn = 1e30f;
    #pragma unroll
    for (int q = 0; q < 8; ++q) {
        const float4 v = row[q];
        mn = fminf(mn, fminf(fminf(v.x, v.y), fminf(v.z, v.w)));
    }
    #pragma unroll
    for (int o = 32; o > 0; o >>= 1) mn += __shfl_xor(mn, o);
    __shared__ float r2[2];
    if ((t & 63) == 0) r2[t >> 6] = mn;
    __syncthreads();
    if (t == 0) {
        const float rec = (r2[0] + r2[1]) * (1.0f / (NB * NS));
        const float kld = klsum[0] * (1.0f / (float)NKL);
        out[0] = fmaf(0.0002f, kld, rec);
        out[1] = rec;
        out[2] = kld;
    }
}

extern "C" void kernel_launch(void* const* d_in, const int* in_sizes, int n_in,
                              void* d_out, int out_size, void* d_ws, size_t ws_size,
                              hipStream_t stream)
{
    const float* ge = (const float*)d_in[0];
    const float* g3 = (const float*)d_in[1];
    const float* pe = (const float*)d_in[2];
    const float* p3 = (const float*)d_in[3];
    const float* mu = (const float*)d_in[4];
    const float* sc = (const float*)d_in[5];

    float* cost  = (float*)d_ws;            // 4096 floats
    float* klsum = cost + NB * NS * NA;     // 1 float

    hipMemsetAsync(d_ws, 0, (NB * NS * NA + 1) * sizeof(float), stream);

    fused_kernel<<<COST_BLOCKS + KL_BLOCKS, 256, 0, stream>>>(
        ge, g3, pe, p3, mu, sc, cost, klsum);
    finalize_kernel<<<1, 128, 0, stream>>>(cost, klsum, (float*)d_out);
}